// Round 8
// baseline (246.245 us; speedup 1.0000x reference)
//
#include <hip/hip_runtime.h>
#include <stdint.h>

typedef unsigned short u16;
typedef float f32x4 __attribute__((ext_vector_type(4)));
typedef short bf16x8 __attribute__((ext_vector_type(8)));

#define DEV __device__ __forceinline__

DEV u16 f2bf(float f) {
  union { float f; unsigned int u; } v; v.f = f;
  unsigned int u = v.u;
  u = (u + 0x7FFFu + ((u >> 16) & 1u)) >> 16;
  return (u16)u;
}

DEV float exp2_(float x) {
#if __has_builtin(__builtin_amdgcn_exp2f)
  return __builtin_amdgcn_exp2f(x);
#else
  return exp2f(x);
#endif
}

DEV unsigned int cvt_pk_bf16(float lo, float hi) {
  unsigned int r;
  asm("v_cvt_pk_bf16_f32 %0, %1, %2" : "=v"(r) : "v"(lo), "v"(hi));
  return r;
}

typedef __attribute__((address_space(1))) const unsigned int* gas_t;
typedef __attribute__((address_space(3))) unsigned int* las_t;
DEV void gload16(const void* g, void* l) {
  // direct global->LDS DMA, 16B/lane; LDS dest = wave-uniform base + lane*16
  __builtin_amdgcn_global_load_lds((gas_t)g, (las_t)l, 16, 0, 0);
}

DEV f32x4 zf4() { f32x4 z = {0.f, 0.f, 0.f, 0.f}; return z; }

// geometry: B=16 C=512 N=1024 G=32 heads=8 ch=64
static constexpr float QK_SCALE = 0.35355339059327373f;  // 64^-0.25
static constexpr float LOG2E    = 1.4426950408889634f;

// workspace offsets (bytes)
static constexpr size_t OFF_WQKV  = 0;          // 1536*512 bf16
static constexpr size_t OFF_WPROJ = 1572864;    // 512*512 bf16
static constexpr size_t OFF_XNT   = 2097152;    // [16][1024][512] bf16 (n-major)
static constexpr size_t OFF_Q     = 18874368;   // [128][1024][64] bf16 (pre-scaled)
static constexpr size_t OFF_K     = 35651584;   // [128][1024][64] bf16 (pre-scaled by scale*log2e)
static constexpr size_t OFF_V     = 52428800;   // [128][64][1024] bf16
static constexpr size_t OFF_HT    = 69206016;   // [16][1024][512] bf16

// ---------------- fused prep: GroupNorm (blocks 0..511) + weight conv (512..1535) ----------------
__global__ __launch_bounds__(256) void prep_kernel(const float* __restrict__ x,
                                                   const float* __restrict__ gamma,
                                                   const float* __restrict__ beta,
                                                   const float* __restrict__ wqkv,
                                                   const float* __restrict__ wproj,
                                                   u16* __restrict__ xnt,
                                                   u16* __restrict__ dq, u16* __restrict__ dp) {
  int tid = threadIdx.x;
  int blk = blockIdx.x;
  if (blk >= 512) {
    int i = (blk - 512) * 256 + tid;  // 262144 float4 total
    const float4* src; u16* dst; int j;
    if (i < 196608) { src = (const float4*)wqkv;  dst = dq; j = i; }
    else            { src = (const float4*)wproj; dst = dp; j = i - 196608; }
    float4 v = src[j];
    uint2 o; o.x = cvt_pk_bf16(v.x, v.y); o.y = cvt_pk_bf16(v.z, v.w);
    *(uint2*)(dst + (size_t)j * 4) = o;
    return;
  }
  __shared__ float rs[4], rss[4], bcast[2];
  int b = blk >> 5, g = blk & 31;
  const float4* p = (const float4*)(x + (size_t)blk * 16384);
  float4 v[16];
  float s = 0.f, ss = 0.f;
  #pragma unroll
  for (int it = 0; it < 16; ++it) {
    v[it] = p[it * 256 + tid];
    s  += v[it].x + v[it].y + v[it].z + v[it].w;
    ss += v[it].x*v[it].x + v[it].y*v[it].y + v[it].z*v[it].z + v[it].w*v[it].w;
  }
  #pragma unroll
  for (int off = 32; off > 0; off >>= 1) {
    s  += __shfl_down(s, off);
    ss += __shfl_down(ss, off);
  }
  int wid = tid >> 6;
  if ((tid & 63) == 0) { rs[wid] = s; rss[wid] = ss; }
  __syncthreads();
  if (tid == 0) {
    s  = rs[0] + rs[1] + rs[2] + rs[3];
    ss = rss[0] + rss[1] + rss[2] + rss[3];
    float mean = s * (1.f / 16384.f);
    float var  = ss * (1.f / 16384.f) - mean * mean;
    bcast[0] = mean;
    bcast[1] = rsqrtf(var + 1e-5f);
  }
  __syncthreads();
  float mean = bcast[0], rstd = bcast[1];
  float ga[16], be[16];
  #pragma unroll
  for (int it = 0; it < 16; ++it) {
    float gm = gamma[g*16 + it];
    ga[it] = gm * rstd;
    be[it] = beta[g*16 + it] - mean * ga[it];
  }
  u16* dst = xnt + ((size_t)(b*1024 + tid*4)) * 512 + g*16;
  #pragma unroll
  for (int k = 0; k < 4; ++k) {
    unsigned int w[8];
    #pragma unroll
    for (int j = 0; j < 8; ++j) {
      float e, o;
      switch (k) {
        case 0: e = v[2*j].x; o = v[2*j+1].x; break;
        case 1: e = v[2*j].y; o = v[2*j+1].y; break;
        case 2: e = v[2*j].z; o = v[2*j+1].z; break;
        default: e = v[2*j].w; o = v[2*j+1].w; break;
      }
      w[j] = cvt_pk_bf16(e*ga[2*j] + be[2*j], o*ga[2*j+1] + be[2*j+1]);
    }
    uint4 lo; lo.x = w[0]; lo.y = w[1]; lo.z = w[2]; lo.w = w[3];
    uint4 hi; hi.x = w[4]; hi.y = w[5]; hi.z = w[6]; hi.w = w[7];
    *(uint4*)(dst + (size_t)k*512)     = lo;
    *(uint4*)(dst + (size_t)k*512 + 8) = hi;
  }
}

// ---------------- GEMM: D[o][n'] = A[o][c] * Bm[n'][c]^T  (K=512) ----------------
// BK=32 double-buffered global_load_lds staging: 32 KB LDS -> 5 blocks/CU.
// Linear LDS both sides (64B row stride gives exactly-balanced bank access; no swizzle).
// EPI=0: qkv epilogue -> Q/K/V per-head layouts (+bias; q *= scale, k *= scale*log2e)
// EPI=1: proj epilogue -> out = acc + bias + x (fp32)
template<int EPI>
__global__ __launch_bounds__(256, 5) void gemm_kernel(const u16* __restrict__ A,
                                                      const u16* __restrict__ Bm,
                                                      const float* __restrict__ bias,
                                                      u16* __restrict__ Qp, u16* __restrict__ Kp,
                                                      u16* __restrict__ Vp,
                                                      const float* __restrict__ xres,
                                                      float* __restrict__ outp) {
  __shared__ u16 lds[2 * 8192];   // buf{A 128x32, B 128x32} x2, 32 KB
  int tid = threadIdx.x, lane = tid & 63, wid = tid >> 6;
  int tl = lane & 15, g = lane >> 4;
  int wm = wid >> 1, wn = wid & 1;
  int tM = blockIdx.y, tN = blockIdx.x;
  int o0 = tM * 128, n0 = tN * 128;
  f32x4 acc[4][4];
  #pragma unroll
  for (int i = 0; i < 4; ++i)
    #pragma unroll
    for (int j = 0; j < 4; ++j) acc[i][j] = zf4();

  // staging: wave `wid` stages rows [32*wid, 32*wid+32) of A and B.
  // lane -> row wid*32 + q*16 + (lane>>2), colseg (lane&3)*8 u16; LDS linear.
  const u16* Ag = A  + (size_t)(o0 + wid*32 + (lane >> 2)) * 512 + (lane & 3) * 8;
  const u16* Bg = Bm + (size_t)(n0 + wid*32 + (lane >> 2)) * 512 + (lane & 3) * 8;
  int wofs = wid * 1024;

#define STAGE_GEMM(buf, kt)                                                     \
  {                                                                             \
    u16* Ad = lds + (buf)*8192 + wofs;                                          \
    u16* Bd = lds + (buf)*8192 + 4096 + wofs;                                   \
    _Pragma("unroll")                                                           \
    for (int q = 0; q < 2; ++q) {                                               \
      gload16(Ag + (size_t)q*16*512 + (kt)*32, Ad + q*512);                     \
      gload16(Bg + (size_t)q*16*512 + (kt)*32, Bd + q*512);                     \
    }                                                                           \
  }

  STAGE_GEMM(0, 0);
  __syncthreads();
  for (int kt = 0; kt < 16; ++kt) {
    int cur = kt & 1;
    if (kt < 15) STAGE_GEMM(cur ^ 1, kt + 1);
    const u16* Als = lds + cur*8192;
    const u16* Bls = lds + cur*8192 + 4096;
    bf16x8 av[4], bv[4];
    #pragma unroll
    for (int mi = 0; mi < 4; ++mi)
      av[mi] = *(const bf16x8*)&Als[(wm*64 + mi*16 + tl)*32 + g*8];
    #pragma unroll
    for (int ni = 0; ni < 4; ++ni)
      bv[ni] = *(const bf16x8*)&Bls[(wn*64 + ni*16 + tl)*32 + g*8];
    #pragma unroll
    for (int mi = 0; mi < 4; ++mi)
      #pragma unroll
      for (int ni = 0; ni < 4; ++ni)
        acc[mi][ni] = __builtin_amdgcn_mfma_f32_16x16x32_bf16(av[mi], bv[ni], acc[mi][ni], 0, 0, 0);
    __syncthreads();
  }
#undef STAGE_GEMM

  if (EPI == 1) {
    // proj: out[b][o][n] = acc + bias[o] + x[b][o][n]
    #pragma unroll
    for (int mi = 0; mi < 4; ++mi) {
      int mb = mi*16 + (g << 2);
      float4 bs = *(const float4*)&bias[o0 + wm*64 + mb];
      const float* bsf = (const float*)&bs;
      #pragma unroll
      for (int ni = 0; ni < 4; ++ni) {
        int n_g = n0 + wn*64 + ni*16 + tl;
        int bb = n_g >> 10, n = n_g & 1023;
        #pragma unroll
        for (int rr = 0; rr < 4; ++rr) {
          int o_g = o0 + wm*64 + mb + rr;
          size_t oi = (((size_t)(bb*512 + o_g)) << 10) + n;
          outp[oi] = acc[mi][ni][rr] + bsf[rr] + xres[oi];
        }
      }
    }
    return;
  }

  // qkv epilogue. head = a/3, sect = a%3 (0=q,1=k,2=v)
  int a = 2*tM + wm;            // 0..23
  int head = a / 3;
  int sect = a - head*3;
  float sc = (sect == 0) ? QK_SCALE : (sect == 1 ? QK_SCALE * LOG2E : 1.f);
  u16* wl = lds + wid * 4096;   // per-wave 64x64 staging, XOR-swizzled
  #pragma unroll
  for (int mi = 0; mi < 4; ++mi) {
    int mb = mi*16 + (g << 2);
    float4 bs = *(const float4*)&bias[o0 + wm*64 + mb];
    const float* bsf = (const float*)&bs;
    #pragma unroll
    for (int ni = 0; ni < 4; ++ni) {
      int nl = ni*16 + tl;
      #pragma unroll
      for (int rr = 0; rr < 4; ++rr) {
        float val = (acc[mi][ni][rr] + bsf[rr]) * sc;
        int ml = mb + rr;
        if (sect < 2) wl[nl*64 + (ml ^ ((nl & 7) << 3))] = f2bf(val);   // [n][c] for Q/K
        else          wl[ml*64 + (nl ^ ((ml & 7) << 3))] = f2bf(val);   // [c][n] for V
      }
    }
  }
  int n_wb = n0 + wn*64;
  int bb = n_wb >> 10, nn0 = n_wb & 1023;
  int bh = bb*8 + head;
  #pragma unroll
  for (int p = 0; p < 8; ++p) {
    int row = p*8 + (lane >> 3), sgg = lane & 7;
    uint4 v = *(const uint4*)&wl[row*64 + ((sgg ^ (row & 7)) << 3)];
    if (sect == 0)
      *(uint4*)(Qp + (((size_t)bh) << 16) + (size_t)(nn0 + row)*64 + sgg*8) = v;
    else if (sect == 1)
      *(uint4*)(Kp + (((size_t)bh) << 16) + (size_t)(nn0 + row)*64 + sgg*8) = v;
    else
      *(uint4*)(Vp + (((size_t)bh) << 16) + (size_t)row*1024 + nn0 + sgg*8) = v;
  }
}

// ---------------- flash attention, swapped-operand, no-max softmax ----------------
// (byte-identical to the r4/r5/r6 passing version; r7's dbuf variant reverted —
// 48KB LDS cost residency and regressed 45->59 us)
__global__ __launch_bounds__(256, 4) void attn_kernel(const u16* __restrict__ Qp,
                                                      const u16* __restrict__ Kp,
                                                      const u16* __restrict__ Vp,
                                                      u16* __restrict__ Hp) {
  __shared__ u16 Kls[64 * 64];
  __shared__ u16 Vls[64 * 64];
  __shared__ u16 Pls[4 * 32 * 64];
  int tid = threadIdx.x, lane = tid & 63, w = tid >> 6;
  int id = blockIdx.x;
  int bh = ((id >> 6) << 3) | (id & 7);   // same-bh blocks share XCD
  int tblk = (id >> 3) & 7;
  int t0 = tblk * 128 + w * 32;
  size_t hb = ((size_t)bh) << 16;
  int tl = lane & 15, g = lane >> 4;

  // Q fragments (B-operand), hoisted: bq[tf][kk]
  bf16x8 bq[2][2];
  #pragma unroll
  for (int tf = 0; tf < 2; ++tf)
    #pragma unroll
    for (int kk = 0; kk < 2; ++kk)
      bq[tf][kk] = *(const bf16x8*)(Qp + hb + (size_t)(t0 + tf*16 + tl)*64 + kk*32 + g*8);

  f32x4 oacc[4][2];   // O^T[c][t]: c = 16ci+4g+r, t = 16tf+tl
  #pragma unroll
  for (int ci = 0; ci < 4; ++ci)
    #pragma unroll
    for (int tf = 0; tf < 2; ++tf) oacc[ci][tf] = zf4();
  float l_run[2] = {0.f, 0.f};   // per-lane partials; reduced once at end
  u16* pw = Pls + w * (32 * 64);
  int sr = tid >> 3, sseg = tid & 7;
  int xsw = (tl & 7) << 3;   // XOR swizzle for frag reads (u16 units)

  for (int s0 = 0; s0 < 1024; s0 += 64) {
    #pragma unroll
    for (int p = 0; p < 2; ++p) {
      int row = p*32 + sr;
      int woff = row*64 + ((sseg ^ (row & 7)) << 3);
      *(uint4*)&Kls[woff] = *(const uint4*)(Kp + hb + (size_t)(s0 + row)*64 + sseg*8);
      *(uint4*)&Vls[woff] = *(const uint4*)(Vp + hb + (size_t)row*1024 + s0 + sseg*8);
    }
    __syncthreads();

    // QK^T: S^T[s][t], lane holds s = 16ni+4g+r for col t = 16tf+tl
    f32x4 sfr[2][4];
    #pragma unroll
    for (int tf = 0; tf < 2; ++tf)
      #pragma unroll
      for (int ni = 0; ni < 4; ++ni) sfr[tf][ni] = zf4();
    __builtin_amdgcn_s_setprio(1);
    #pragma unroll
    for (int kk = 0; kk < 2; ++kk) {
      bf16x8 ak[4];
      #pragma unroll
      for (int ni = 0; ni < 4; ++ni)
        ak[ni] = *(const bf16x8*)&Kls[(ni*16 + tl)*64 + ((((kk*4 + g) << 3)) ^ xsw)];
      #pragma unroll
      for (int tf = 0; tf < 2; ++tf)
        #pragma unroll
        for (int ni = 0; ni < 4; ++ni)
          sfr[tf][ni] = __builtin_amdgcn_mfma_f32_16x16x32_bf16(ak[ni], bq[tf][kk], sfr[tf][ni], 0, 0, 0);
    }
    __builtin_amdgcn_s_setprio(0);

    // softmax-lite: p = exp2(s), accumulate per-lane l, pack to LDS
    #pragma unroll
    for (int tf = 0; tf < 2; ++tf) {
      int trow = tf*16 + tl;
      int rsw = (trow & 7) << 3;
      float lt = 0.f;
      #pragma unroll
      for (int ni = 0; ni < 4; ++ni) {
        float p0 = exp2_(sfr[tf][ni][0]);
        float p1 = exp2_(sfr[tf][ni][1]);
        float p2 = exp2_(sfr[tf][ni][2]);
        float p3 = exp2_(sfr[tf][ni][3]);
        lt += (p0 + p1) + (p2 + p3);
        uint2 pkv;
        pkv.x = cvt_pk_bf16(p0, p1);
        pkv.y = cvt_pk_bf16(p2, p3);
        *(uint2*)&pw[trow*64 + ((ni*16 + g*4) ^ rsw)] = pkv;
      }
      l_run[tf] += lt;
    }

    // PV: O^T[c][t] += V[c][s] . P^T[s][t]
    __builtin_amdgcn_s_setprio(1);
    #pragma unroll
    for (int kk = 0; kk < 2; ++kk) {
      bf16x8 av[4];
      #pragma unroll
      for (int ci = 0; ci < 4; ++ci)
        av[ci] = *(const bf16x8*)&Vls[(ci*16 + tl)*64 + ((((kk*4 + g) << 3)) ^ xsw)];
      #pragma unroll
      for (int tf = 0; tf < 2; ++tf) {
        int trow = tf*16 + tl;
        bf16x8 bp = *(const bf16x8*)&pw[trow*64 + (((kk*4 + g) << 3) ^ ((trow & 7) << 3))];
        #pragma unroll
        for (int ci = 0; ci < 4; ++ci)
          oacc[ci][tf] = __builtin_amdgcn_mfma_f32_16x16x32_bf16(av[ci], bp, oacc[ci][tf], 0, 0, 0);
      }
    }
    __builtin_amdgcn_s_setprio(0);
    __syncthreads();
  }

  // epilogue: reduce l across the 4 g-lanes, normalize, transpose via LDS, store
  #pragma unroll
  for (int tf = 0; tf < 2; ++tf) {
    float l = l_run[tf];
    l += __shfl_xor(l, 16);
    l += __shfl_xor(l, 32);
    float inv = 1.f / l;
    int trow = tf*16 + tl;
    int rsw = (trow & 7) << 3;
    #pragma unroll
    for (int ci = 0; ci < 4; ++ci) {
      uint2 pkv;
      pkv.x = cvt_pk_bf16(oacc[ci][tf][0]*inv, oacc[ci][tf][1]*inv);
      pkv.y = cvt_pk_bf16(oacc[ci][tf][2]*inv, oacc[ci][tf][3]*inv);
      *(uint2*)&pw[trow*64 + ((ci*16 + g*4) ^ rsw)] = pkv;
    }
  }
  int b = bh >> 3, head = bh & 7;
  #pragma unroll
  for (int p = 0; p < 4; ++p) {
    int row = p*8 + (lane >> 3), sgg = lane & 7;
    uint4 v = *(const uint4*)&pw[row*64 + ((sgg ^ (row & 7)) << 3)];
    *(uint4*)(Hp + ((size_t)(b*1024 + t0 + row))*512 + head*64 + sgg*8) = v;
  }
}

extern "C" void kernel_launch(void* const* d_in, const int* in_sizes, int n_in,
                              void* d_out, int out_size, void* d_ws, size_t ws_size,
                              hipStream_t stream) {
  const float* x     = (const float*)d_in[0];
  const float* gamma = (const float*)d_in[1];
  const float* beta  = (const float*)d_in[2];
  const float* wqkv  = (const float*)d_in[3];
  const float* bqkv  = (const float*)d_in[4];
  const float* wproj = (const float*)d_in[5];
  const float* bproj = (const float*)d_in[6];
  float* out = (float*)d_out;
  char* ws = (char*)d_ws;
  u16* wqkv_bf  = (u16*)(ws + OFF_WQKV);
  u16* wproj_bf = (u16*)(ws + OFF_WPROJ);
  u16* xnt = (u16*)(ws + OFF_XNT);
  u16* Qp  = (u16*)(ws + OFF_Q);
  u16* Kp  = (u16*)(ws + OFF_K);
  u16* Vp  = (u16*)(ws + OFF_V);
  u16* Hp  = (u16*)(ws + OFF_HT);

  prep_kernel<<<1536, 256, 0, stream>>>(x, gamma, beta, wqkv, wproj, xnt, wqkv_bf, wproj_bf);
  gemm_kernel<0><<<dim3(128, 12), 256, 0, stream>>>(wqkv_bf, xnt, bqkv, Qp, Kp, Vp, nullptr, nullptr);
  attn_kernel<<<1024, 256, 0, stream>>>(Qp, Kp, Vp, Hp);
  gemm_kernel<1><<<dim3(128, 4), 256, 0, stream>>>(wproj_bf, Hp, bproj, nullptr, nullptr, nullptr, x, out);
}

// Round 9
// 189.189 us; speedup vs baseline: 1.3016x; 1.3016x over previous
//
#include <hip/hip_runtime.h>
#include <stdint.h>

typedef unsigned short u16;
typedef float f32x4 __attribute__((ext_vector_type(4)));
typedef short bf16x8 __attribute__((ext_vector_type(8)));

#define DEV __device__ __forceinline__

DEV u16 f2bf(float f) {
  union { float f; unsigned int u; } v; v.f = f;
  unsigned int u = v.u;
  u = (u + 0x7FFFu + ((u >> 16) & 1u)) >> 16;
  return (u16)u;
}

DEV float exp2_(float x) {
#if __has_builtin(__builtin_amdgcn_exp2f)
  return __builtin_amdgcn_exp2f(x);
#else
  return exp2f(x);
#endif
}

DEV unsigned int cvt_pk_bf16(float lo, float hi) {
  unsigned int r;
  asm("v_cvt_pk_bf16_f32 %0, %1, %2" : "=v"(r) : "v"(lo), "v"(hi));
  return r;
}

typedef __attribute__((address_space(1))) const unsigned int* gas_t;
typedef __attribute__((address_space(3))) unsigned int* las_t;
DEV void gload16(const void* g, void* l) {
  // direct global->LDS DMA, 16B/lane; LDS dest = wave-uniform base + lane*16
  __builtin_amdgcn_global_load_lds((gas_t)g, (las_t)l, 16, 0, 0);
}

DEV f32x4 zf4() { f32x4 z = {0.f, 0.f, 0.f, 0.f}; return z; }

// geometry: B=16 C=512 N=1024 G=32 heads=8 ch=64
static constexpr float QK_SCALE = 0.35355339059327373f;  // 64^-0.25
static constexpr float LOG2E    = 1.4426950408889634f;

// workspace offsets (bytes)
static constexpr size_t OFF_WQKV  = 0;          // 1536*512 bf16
static constexpr size_t OFF_WPROJ = 1572864;    // 512*512 bf16
static constexpr size_t OFF_XNT   = 2097152;    // [16][1024][512] bf16 (n-major)
static constexpr size_t OFF_Q     = 18874368;   // [128][1024][64] bf16 (pre-scaled)
static constexpr size_t OFF_K     = 35651584;   // [128][1024][64] bf16 (pre-scaled by scale*log2e)
static constexpr size_t OFF_V     = 52428800;   // [128][64][1024] bf16
static constexpr size_t OFF_HT    = 69206016;   // [16][1024][512] bf16

// ---------------- fused prep: GroupNorm (blocks 0..511) + weight conv (512..1535) ----------------
__global__ __launch_bounds__(256) void prep_kernel(const float* __restrict__ x,
                                                   const float* __restrict__ gamma,
                                                   const float* __restrict__ beta,
                                                   const float* __restrict__ wqkv,
                                                   const float* __restrict__ wproj,
                                                   u16* __restrict__ xnt,
                                                   u16* __restrict__ dq, u16* __restrict__ dp) {
  int tid = threadIdx.x;
  int blk = blockIdx.x;
  if (blk >= 512) {
    int i = (blk - 512) * 256 + tid;  // 262144 float4 total
    const float4* src; u16* dst; int j;
    if (i < 196608) { src = (const float4*)wqkv;  dst = dq; j = i; }
    else            { src = (const float4*)wproj; dst = dp; j = i - 196608; }
    float4 v = src[j];
    uint2 o; o.x = cvt_pk_bf16(v.x, v.y); o.y = cvt_pk_bf16(v.z, v.w);
    *(uint2*)(dst + (size_t)j * 4) = o;
    return;
  }
  __shared__ float rs[4], rss[4], bcast[2];
  int b = blk >> 5, g = blk & 31;
  const float4* p = (const float4*)(x + (size_t)blk * 16384);
  float4 v[16];
  float s = 0.f, ss = 0.f;
  #pragma unroll
  for (int it = 0; it < 16; ++it) {
    v[it] = p[it * 256 + tid];
    s  += v[it].x + v[it].y + v[it].z + v[it].w;
    ss += v[it].x*v[it].x + v[it].y*v[it].y + v[it].z*v[it].z + v[it].w*v[it].w;
  }
  #pragma unroll
  for (int off = 32; off > 0; off >>= 1) {
    s  += __shfl_down(s, off);
    ss += __shfl_down(ss, off);
  }
  int wid = tid >> 6;
  if ((tid & 63) == 0) { rs[wid] = s; rss[wid] = ss; }
  __syncthreads();
  if (tid == 0) {
    s  = rs[0] + rs[1] + rs[2] + rs[3];
    ss = rss[0] + rss[1] + rss[2] + rss[3];
    float mean = s * (1.f / 16384.f);
    float var  = ss * (1.f / 16384.f) - mean * mean;
    bcast[0] = mean;
    bcast[1] = rsqrtf(var + 1e-5f);
  }
  __syncthreads();
  float mean = bcast[0], rstd = bcast[1];
  float ga[16], be[16];
  #pragma unroll
  for (int it = 0; it < 16; ++it) {
    float gm = gamma[g*16 + it];
    ga[it] = gm * rstd;
    be[it] = beta[g*16 + it] - mean * ga[it];
  }
  u16* dst = xnt + ((size_t)(b*1024 + tid*4)) * 512 + g*16;
  #pragma unroll
  for (int k = 0; k < 4; ++k) {
    unsigned int w[8];
    #pragma unroll
    for (int j = 0; j < 8; ++j) {
      float e, o;
      switch (k) {
        case 0: e = v[2*j].x; o = v[2*j+1].x; break;
        case 1: e = v[2*j].y; o = v[2*j+1].y; break;
        case 2: e = v[2*j].z; o = v[2*j+1].z; break;
        default: e = v[2*j].w; o = v[2*j+1].w; break;
      }
      w[j] = cvt_pk_bf16(e*ga[2*j] + be[2*j], o*ga[2*j+1] + be[2*j+1]);
    }
    uint4 lo; lo.x = w[0]; lo.y = w[1]; lo.z = w[2]; lo.w = w[3];
    uint4 hi; hi.x = w[4]; hi.y = w[5]; hi.z = w[6]; hi.w = w[7];
    *(uint4*)(dst + (size_t)k*512)     = lo;
    *(uint4*)(dst + (size_t)k*512 + 8) = hi;
  }
}

// ---------------- GEMM: D[o][n'] = A[o][c] * Bm[n'][c]^T  (K=512) ----------------
// r6-validated: BK=64 double-buffered global_load_lds staging; STAGE(buf^1, kt+1)
// before compute on buf; one full-drain __syncthreads per K-step.
// EPI=0: qkv epilogue -> Q/K/V per-head layouts (+bias; q *= scale, k *= scale*log2e)
// EPI=1: proj epilogue -> out = acc + bias + x (fp32)
template<int EPI>
__global__ __launch_bounds__(256) void gemm_kernel(const u16* __restrict__ A,
                                                   const u16* __restrict__ Bm,
                                                   const float* __restrict__ bias,
                                                   u16* __restrict__ Qp, u16* __restrict__ Kp,
                                                   u16* __restrict__ Vp,
                                                   const float* __restrict__ xres,
                                                   float* __restrict__ outp) {
  __shared__ u16 lds[4 * 128 * 64];   // buf0{A,B} | buf1{A,B}, 64 KB
  int tid = threadIdx.x, lane = tid & 63, wid = tid >> 6;
  int tl = lane & 15, g = lane >> 4;
  int wm = wid >> 1, wn = wid & 1;
  int tM = blockIdx.y, tN = blockIdx.x;
  int o0 = tM * 128, n0 = tN * 128;
  f32x4 acc[4][4];
  #pragma unroll
  for (int i = 0; i < 4; ++i)
    #pragma unroll
    for (int j = 0; j < 4; ++j) acc[i][j] = zf4();

  // staging: wave `wid` stages rows [32*wid, 32*wid+32) of A and B.
  // lane (rl,sg) -> LDS row rl (linear), global col block sg^rl (pre-swizzle).
  int rl = lane >> 3, sg = lane & 7;
  const u16* Ag = A  + (size_t)(o0 + wid*32 + rl) * 512 + ((sg ^ rl) << 3);
  const u16* Bg = Bm + (size_t)(n0 + wid*32 + rl) * 512 + ((sg ^ rl) << 3);
  int wofs = wid*32*64;

#define STAGE_GEMM(buf, kt)                                                     \
  {                                                                             \
    u16* Ad = lds + (buf)*16384 + wofs;                                         \
    u16* Bd = lds + (buf)*16384 + 8192 + wofs;                                  \
    _Pragma("unroll")                                                           \
    for (int q = 0; q < 4; ++q) {                                               \
      gload16(Ag + (size_t)q*8*512 + (kt)*64, Ad + q*8*64);                     \
      gload16(Bg + (size_t)q*8*512 + (kt)*64, Bd + q*8*64);                     \
    }                                                                           \
  }

  STAGE_GEMM(0, 0);
  __syncthreads();
  for (int kt = 0; kt < 8; ++kt) {
    int cur = kt & 1;
    if (kt < 7) STAGE_GEMM(cur ^ 1, kt + 1);
    const u16* Als = lds + cur*16384;
    const u16* Bls = lds + cur*16384 + 8192;
    #pragma unroll
    for (int kk = 0; kk < 2; ++kk) {
      bf16x8 av[4], bv[4];
      #pragma unroll
      for (int mi = 0; mi < 4; ++mi)
        av[mi] = *(const bf16x8*)&Als[(wm*64 + mi*16 + tl)*64 + (((kk*4 + g) ^ (tl & 7)) << 3)];
      #pragma unroll
      for (int ni = 0; ni < 4; ++ni)
        bv[ni] = *(const bf16x8*)&Bls[(wn*64 + ni*16 + tl)*64 + (((kk*4 + g) ^ (tl & 7)) << 3)];
      #pragma unroll
      for (int mi = 0; mi < 4; ++mi)
        #pragma unroll
        for (int ni = 0; ni < 4; ++ni)
          acc[mi][ni] = __builtin_amdgcn_mfma_f32_16x16x32_bf16(av[mi], bv[ni], acc[mi][ni], 0, 0, 0);
    }
    __syncthreads();
  }
#undef STAGE_GEMM

  if (EPI == 1) {
    // proj: out[b][o][n] = acc + bias[o] + x[b][o][n]
    #pragma unroll
    for (int mi = 0; mi < 4; ++mi) {
      int mb = mi*16 + (g << 2);
      float4 bs = *(const float4*)&bias[o0 + wm*64 + mb];
      const float* bsf = (const float*)&bs;
      #pragma unroll
      for (int ni = 0; ni < 4; ++ni) {
        int n_g = n0 + wn*64 + ni*16 + tl;
        int bb = n_g >> 10, n = n_g & 1023;
        #pragma unroll
        for (int rr = 0; rr < 4; ++rr) {
          int o_g = o0 + wm*64 + mb + rr;
          size_t oi = (((size_t)(bb*512 + o_g)) << 10) + n;
          outp[oi] = acc[mi][ni][rr] + bsf[rr] + xres[oi];
        }
      }
    }
    return;
  }

  // qkv epilogue. head = a/3, sect = a%3 (0=q,1=k,2=v)
  int a = 2*tM + wm;            // 0..23
  int head = a / 3;
  int sect = a - head*3;
  float sc = (sect == 0) ? QK_SCALE : (sect == 1 ? QK_SCALE * LOG2E : 1.f);
  u16* wl = lds + wid * (64*64);   // per-wave 64x64 staging, XOR-swizzled
  #pragma unroll
  for (int mi = 0; mi < 4; ++mi) {
    int mb = mi*16 + (g << 2);
    float4 bs = *(const float4*)&bias[o0 + wm*64 + mb];
    const float* bsf = (const float*)&bs;
    #pragma unroll
    for (int ni = 0; ni < 4; ++ni) {
      int nl = ni*16 + tl;
      #pragma unroll
      for (int rr = 0; rr < 4; ++rr) {
        float val = (acc[mi][ni][rr] + bsf[rr]) * sc;
        int ml = mb + rr;
        if (sect < 2) wl[nl*64 + (ml ^ ((nl & 7) << 3))] = f2bf(val);   // [n][c] for Q/K
        else          wl[ml*64 + (nl ^ ((ml & 7) << 3))] = f2bf(val);   // [c][n] for V
      }
    }
  }
  int n_wb = n0 + wn*64;
  int bb = n_wb >> 10, nn0 = n_wb & 1023;
  int bh = bb*8 + head;
  #pragma unroll
  for (int p = 0; p < 8; ++p) {
    int row = p*8 + (lane >> 3), sgg = lane & 7;
    uint4 v = *(const uint4*)&wl[row*64 + ((sgg ^ (row & 7)) << 3)];
    if (sect == 0)
      *(uint4*)(Qp + (((size_t)bh) << 16) + (size_t)(nn0 + row)*64 + sgg*8) = v;
    else if (sect == 1)
      *(uint4*)(Kp + (((size_t)bh) << 16) + (size_t)(nn0 + row)*64 + sgg*8) = v;
    else
      *(uint4*)(Vp + (((size_t)bh) << 16) + (size_t)row*1024 + nn0 + sgg*8) = v;
  }
}

// ---------------- flash attention, swapped-operand, no-max softmax ----------------
// (byte-identical to the r4/r5/r6 passing version)
__global__ __launch_bounds__(256, 4) void attn_kernel(const u16* __restrict__ Qp,
                                                      const u16* __restrict__ Kp,
                                                      const u16* __restrict__ Vp,
                                                      u16* __restrict__ Hp) {
  __shared__ u16 Kls[64 * 64];
  __shared__ u16 Vls[64 * 64];
  __shared__ u16 Pls[4 * 32 * 64];
  int tid = threadIdx.x, lane = tid & 63, w = tid >> 6;
  int id = blockIdx.x;
  int bh = ((id >> 6) << 3) | (id & 7);   // same-bh blocks share XCD
  int tblk = (id >> 3) & 7;
  int t0 = tblk * 128 + w * 32;
  size_t hb = ((size_t)bh) << 16;
  int tl = lane & 15, g = lane >> 4;

  // Q fragments (B-operand), hoisted: bq[tf][kk]
  bf16x8 bq[2][2];
  #pragma unroll
  for (int tf = 0; tf < 2; ++tf)
    #pragma unroll
    for (int kk = 0; kk < 2; ++kk)
      bq[tf][kk] = *(const bf16x8*)(Qp + hb + (size_t)(t0 + tf*16 + tl)*64 + kk*32 + g*8);

  f32x4 oacc[4][2];   // O^T[c][t]: c = 16ci+4g+r, t = 16tf+tl
  #pragma unroll
  for (int ci = 0; ci < 4; ++ci)
    #pragma unroll
    for (int tf = 0; tf < 2; ++tf) oacc[ci][tf] = zf4();
  float l_run[2] = {0.f, 0.f};   // per-lane partials; reduced once at end
  u16* pw = Pls + w * (32 * 64);
  int sr = tid >> 3, sseg = tid & 7;
  int xsw = (tl & 7) << 3;   // XOR swizzle for frag reads (u16 units)

  for (int s0 = 0; s0 < 1024; s0 += 64) {
    #pragma unroll
    for (int p = 0; p < 2; ++p) {
      int row = p*32 + sr;
      int woff = row*64 + ((sseg ^ (row & 7)) << 3);
      *(uint4*)&Kls[woff] = *(const uint4*)(Kp + hb + (size_t)(s0 + row)*64 + sseg*8);
      *(uint4*)&Vls[woff] = *(const uint4*)(Vp + hb + (size_t)row*1024 + s0 + sseg*8);
    }
    __syncthreads();

    // QK^T: S^T[s][t], lane holds s = 16ni+4g+r for col t = 16tf+tl
    f32x4 sfr[2][4];
    #pragma unroll
    for (int tf = 0; tf < 2; ++tf)
      #pragma unroll
      for (int ni = 0; ni < 4; ++ni) sfr[tf][ni] = zf4();
    __builtin_amdgcn_s_setprio(1);
    #pragma unroll
    for (int kk = 0; kk < 2; ++kk) {
      bf16x8 ak[4];
      #pragma unroll
      for (int ni = 0; ni < 4; ++ni)
        ak[ni] = *(const bf16x8*)&Kls[(ni*16 + tl)*64 + ((((kk*4 + g) << 3)) ^ xsw)];
      #pragma unroll
      for (int tf = 0; tf < 2; ++tf)
        #pragma unroll
        for (int ni = 0; ni < 4; ++ni)
          sfr[tf][ni] = __builtin_amdgcn_mfma_f32_16x16x32_bf16(ak[ni], bq[tf][kk], sfr[tf][ni], 0, 0, 0);
    }
    __builtin_amdgcn_s_setprio(0);

    // softmax-lite: p = exp2(s), accumulate per-lane l, pack to LDS
    #pragma unroll
    for (int tf = 0; tf < 2; ++tf) {
      int trow = tf*16 + tl;
      int rsw = (trow & 7) << 3;
      float lt = 0.f;
      #pragma unroll
      for (int ni = 0; ni < 4; ++ni) {
        float p0 = exp2_(sfr[tf][ni][0]);
        float p1 = exp2_(sfr[tf][ni][1]);
        float p2 = exp2_(sfr[tf][ni][2]);
        float p3 = exp2_(sfr[tf][ni][3]);
        lt += (p0 + p1) + (p2 + p3);
        uint2 pkv;
        pkv.x = cvt_pk_bf16(p0, p1);
        pkv.y = cvt_pk_bf16(p2, p3);
        *(uint2*)&pw[trow*64 + ((ni*16 + g*4) ^ rsw)] = pkv;
      }
      l_run[tf] += lt;
    }

    // PV: O^T[c][t] += V[c][s] . P^T[s][t]
    __builtin_amdgcn_s_setprio(1);
    #pragma unroll
    for (int kk = 0; kk < 2; ++kk) {
      bf16x8 av[4];
      #pragma unroll
      for (int ci = 0; ci < 4; ++ci)
        av[ci] = *(const bf16x8*)&Vls[(ci*16 + tl)*64 + ((((kk*4 + g) << 3)) ^ xsw)];
      #pragma unroll
      for (int tf = 0; tf < 2; ++tf) {
        int trow = tf*16 + tl;
        bf16x8 bp = *(const bf16x8*)&pw[trow*64 + (((kk*4 + g) << 3) ^ ((trow & 7) << 3))];
        #pragma unroll
        for (int ci = 0; ci < 4; ++ci)
          oacc[ci][tf] = __builtin_amdgcn_mfma_f32_16x16x32_bf16(av[ci], bp, oacc[ci][tf], 0, 0, 0);
      }
    }
    __builtin_amdgcn_s_setprio(0);
    __syncthreads();
  }

  // epilogue: reduce l across the 4 g-lanes, normalize, transpose via LDS, store
  #pragma unroll
  for (int tf = 0; tf < 2; ++tf) {
    float l = l_run[tf];
    l += __shfl_xor(l, 16);
    l += __shfl_xor(l, 32);
    float inv = 1.f / l;
    int trow = tf*16 + tl;
    int rsw = (trow & 7) << 3;
    #pragma unroll
    for (int ci = 0; ci < 4; ++ci) {
      uint2 pkv;
      pkv.x = cvt_pk_bf16(oacc[ci][tf][0]*inv, oacc[ci][tf][1]*inv);
      pkv.y = cvt_pk_bf16(oacc[ci][tf][2]*inv, oacc[ci][tf][3]*inv);
      *(uint2*)&pw[trow*64 + ((ci*16 + g*4) ^ rsw)] = pkv;
    }
  }
  int b = bh >> 3, head = bh & 7;
  #pragma unroll
  for (int p = 0; p < 4; ++p) {
    int row = p*8 + (lane >> 3), sgg = lane & 7;
    uint4 v = *(const uint4*)&pw[row*64 + ((sgg ^ (row & 7)) << 3)];
    *(uint4*)(Hp + ((size_t)(b*1024 + t0 + row))*512 + head*64 + sgg*8) = v;
  }
}

extern "C" void kernel_launch(void* const* d_in, const int* in_sizes, int n_in,
                              void* d_out, int out_size, void* d_ws, size_t ws_size,
                              hipStream_t stream) {
  const float* x     = (const float*)d_in[0];
  const float* gamma = (const float*)d_in[1];
  const float* beta  = (const float*)d_in[2];
  const float* wqkv  = (const float*)d_in[3];
  const float* bqkv  = (const float*)d_in[4];
  const float* wproj = (const float*)d_in[5];
  const float* bproj = (const float*)d_in[6];
  float* out = (float*)d_out;
  char* ws = (char*)d_ws;
  u16* wqkv_bf  = (u16*)(ws + OFF_WQKV);
  u16* wproj_bf = (u16*)(ws + OFF_WPROJ);
  u16* xnt = (u16*)(ws + OFF_XNT);
  u16* Qp  = (u16*)(ws + OFF_Q);
  u16* Kp  = (u16*)(ws + OFF_K);
  u16* Vp  = (u16*)(ws + OFF_V);
  u16* Hp  = (u16*)(ws + OFF_HT);

  prep_kernel<<<1536, 256, 0, stream>>>(x, gamma, beta, wqkv, wproj, xnt, wqkv_bf, wproj_bf);
  gemm_kernel<0><<<dim3(128, 12), 256, 0, stream>>>(wqkv_bf, xnt, bqkv, Qp, Kp, Vp, nullptr, nullptr);
  attn_kernel<<<1024, 256, 0, stream>>>(Qp, Kp, Vp, Hp);
  gemm_kernel<1><<<dim3(128, 4), 256, 0, stream>>>(wproj_bf, Hp, bproj, nullptr, nullptr, nullptr, x, out);
}